// Round 6
// baseline (372.664 us; speedup 1.0000x reference)
//
#include <hip/hip_runtime.h>
#include <hip/hip_bf16.h>
#include <stdint.h>

// MHA forward: B=4, T=2048, D=1024, H=16, dk=64.  fp32 in/out, bf16 MFMA internally.
// R3: XOR bank-swizzle on all LDS tiles. R4: softmax de-VALU-ized.
// R7: 64-key K/V dbuf tiles, prefetch-after-barrier; XCD-grouping swizzle.
// R8 lesson: 8 barrier-locked waves regressed (lockstep contention).
// R10: PV at K=32 via key-pair remap -> attn 87.3us, bank conflicts 0,
//      MfmaUtil*dur == full-rate MFMA floor.  KEPT (best attn).
// R11 lesson: doubling per-wave query blocking (grid 512) regressed to 89.9 --
//      attn wall is wave-overlap-bound, not LDS-BW-bound; fewer resident
//      blocks lose more than halved LDS traffic gains.  REVERTED.
// R12: attack the ~231us of non-attn time (never visible in top-5).
//      (a) convert_inputs ELIMINATED: gemm_qkv reg-stages A directly from
//          fp32 (2x float4 load -> cvt_pk_bf16 -> ds_write_b128 into the same
//          swizzled layout; B stays async gl2lds).  Kills a 24us pure-BW
//          kernel + ~96MB of HBM round-trip for the bf16 intermediate.
//      (b) GEMM swizzle ordering flipped (bx inner): one 512KB fp32 A-panel +
//          2MB B resident per XCD L2 (old: 8 A-panels = 4MB fp32 > L2).

typedef __bf16 bf16x8 __attribute__((ext_vector_type(8)));
typedef float  f32x4  __attribute__((ext_vector_type(4)));

#define LOG2E 1.44269504088896340736f

static __device__ __forceinline__ uint32_t f2bf(float x) {
  uint32_t u = __float_as_uint(x);
  u += 0x7fffu + ((u >> 16) & 1u);      // RNE
  return u >> 16;
}
#if __has_builtin(__builtin_amdgcn_cvt_pk_bf16_f32)
static __device__ __forceinline__ uint32_t pk2bf(float a, float b) {
  typedef __bf16 b2 __attribute__((ext_vector_type(2)));
  union { b2 v; uint32_t u; } x;
  x.v = __builtin_amdgcn_cvt_pk_bf16_f32(a, b);  // lo=a, hi=b
  return x.u;
}
#else
static __device__ __forceinline__ uint32_t pk2bf(float a, float b) {
  return f2bf(a) | (f2bf(b) << 16);
}
#endif
static __device__ __forceinline__ void gl2lds16(const void* g, void* l) {
  // async global->LDS, 16B/lane; LDS dest = wave-uniform base + lane*16
  __builtin_amdgcn_global_load_lds(
      (const __attribute__((address_space(1))) uint32_t*)g,
      (__attribute__((address_space(3))) uint32_t*)l, 16, 0, 0);
}

// ---------------- W (K x N fp32) -> Wt (N x K bf16) ------------------------
__global__ void transpose_weights(const float* __restrict__ Wq, const float* __restrict__ Wk,
                                  const float* __restrict__ Wv, const float* __restrict__ Wo,
                                  uint16_t* __restrict__ out) {
  __shared__ float t[32][33];
  const float* W = blockIdx.z == 0 ? Wq : blockIdx.z == 1 ? Wk : blockIdx.z == 2 ? Wv : Wo;
  uint16_t* O = out + (size_t)blockIdx.z * 1048576;
  int tx = threadIdx.x & 31, ty = threadIdx.x >> 5;
  int r0 = blockIdx.y * 32, c0 = blockIdx.x * 32;
#pragma unroll
  for (int i = 0; i < 4; i++) t[ty + i * 8][tx] = W[(size_t)(r0 + ty + i * 8) * 1024 + c0 + tx];
  __syncthreads();
#pragma unroll
  for (int i = 0; i < 4; i++)
    O[(size_t)(c0 + ty + i * 8) * 1024 + r0 + tx] = (uint16_t)f2bf(t[tx][ty + i * 8]);
}

// ---------------- bf16 GEMM body: C = (A(MxK) * Bt(NxK)^T + bias) * oscale -
// Single-buffered 128x64 LDS tiles (8 chunks of 16B); XOR chunk swizzle by row&7.
// AF32: A is fp32, reg-staged + cvt_pk + ds_write (fused input conversion).
//       else A is bf16 via async gl2lds.
// mode 0: fp32 natural   mode 1: bf16 natural   mode 2: bf16 V-transposed per head
template <bool AF32>
static __device__ __forceinline__ void gemm_body(
    const void* __restrict__ Ain, const uint16_t* __restrict__ Bt,
    const float* __restrict__ bias, void* __restrict__ Cout,
    int N, int K, int mode, float oscale, int mBase, int nBase,
    uint16_t* __restrict__ lA, uint16_t* __restrict__ lB) {
  int tid = threadIdx.x, wave = tid >> 6, lane = tid & 63;
  int q = lane >> 4, c = lane & 15;
  int wrow = wave & 1, wcol = wave >> 1;
  f32x4 acc[4][4] = {};

  int rho = lane >> 3, j = lane & 7;
  int swz = (j ^ rho) * 8;
  const uint16_t* gB  = Bt + (size_t)(nBase + wave * 32 + rho) * K + swz;
  const uint16_t* gA16 = (const uint16_t*)Ain + (size_t)(mBase + wave * 32 + rho) * K + swz;
  const float*    gA32 = (const float*)Ain + (size_t)(mBase + wave * 32 + rho) * K + swz;
  int cs = c & 7;

  for (int kt = 0; kt < K / 64; kt++) {
    __syncthreads();
    int k0 = kt * 64;
#pragma unroll
    for (int it = 0; it < 4; it++)
      gl2lds16(gB + (size_t)(it * 8) * K + k0, &lB[(wave * 32 + it * 8) * 64]);
    if (AF32) {
      // fused fp32->bf16 A staging; two 4-load halves bound VGPR
#pragma unroll
      for (int h2 = 0; h2 < 2; h2++) {
        float4 fa[2][2];
#pragma unroll
        for (int it = 0; it < 2; it++) {
          const float* p = gA32 + (size_t)((h2 * 2 + it) * 8) * K + k0;
          fa[it][0] = *(const float4*)p;
          fa[it][1] = *(const float4*)(p + 4);
        }
#pragma unroll
        for (int it = 0; it < 2; it++) {
          uint4 ov;
          ov.x = pk2bf(fa[it][0].x, fa[it][0].y);
          ov.y = pk2bf(fa[it][0].z, fa[it][0].w);
          ov.z = pk2bf(fa[it][1].x, fa[it][1].y);
          ov.w = pk2bf(fa[it][1].z, fa[it][1].w);
          *(uint4*)&lA[(wave * 32 + (h2 * 2 + it) * 8 + rho) * 64 + j * 8] = ov;
        }
      }
    } else {
#pragma unroll
      for (int it = 0; it < 4; it++)
        gl2lds16(gA16 + (size_t)(it * 8) * K + k0, &lA[(wave * 32 + it * 8) * 64]);
    }
    __syncthreads();
#pragma unroll
    for (int kk = 0; kk < 2; kk++) {
      bf16x8 af[4], bfr[4];
#pragma unroll
      for (int i = 0; i < 4; i++)
        af[i] = *(const bf16x8*)&lA[(wrow * 64 + i * 16 + c) * 64 + ((kk * 4 + q) ^ cs) * 8];
#pragma unroll
      for (int jj = 0; jj < 4; jj++)
        bfr[jj] = *(const bf16x8*)&lB[(wcol * 64 + jj * 16 + c) * 64 + ((kk * 4 + q) ^ cs) * 8];
#pragma unroll
      for (int i = 0; i < 4; i++)
#pragma unroll
        for (int jj = 0; jj < 4; jj++)
          acc[i][jj] = __builtin_amdgcn_mfma_f32_16x16x32_bf16(af[i], bfr[jj], acc[i][jj], 0, 0, 0);
    }
  }

  float bb[4];
#pragma unroll
  for (int jj = 0; jj < 4; jj++) bb[jj] = bias[nBase + wcol * 64 + jj * 16 + c];

  if (mode == 0) {
    float* Co = (float*)Cout;
#pragma unroll
    for (int i = 0; i < 4; i++)
#pragma unroll
      for (int jj = 0; jj < 4; jj++) {
        int row = mBase + wrow * 64 + i * 16 + q * 4;
        int col = nBase + wcol * 64 + jj * 16 + c;
#pragma unroll
        for (int r = 0; r < 4; r++) Co[(size_t)(row + r) * N + col] = acc[i][jj][r] + bb[jj];
      }
  } else if (mode == 1) {
    uint16_t* Co = (uint16_t*)Cout;
#pragma unroll
    for (int i = 0; i < 4; i++)
#pragma unroll
      for (int jj = 0; jj < 4; jj++) {
        int row = mBase + wrow * 64 + i * 16 + q * 4;
        int col = nBase + wcol * 64 + jj * 16 + c;
#pragma unroll
        for (int r = 0; r < 4; r++)
          Co[(size_t)(row + r) * N + col] = (uint16_t)f2bf((acc[i][jj][r] + bb[jj]) * oscale);
      }
  } else {  // V: write Vt[(b*16+h)*64+d][t]
    uint16_t* Co = (uint16_t*)Cout;
#pragma unroll
    for (int i = 0; i < 4; i++)
#pragma unroll
      for (int jj = 0; jj < 4; jj++) {
        int n = nBase + wcol * 64 + jj * 16 + c;
        int h = n >> 6, d = n & 63;
        int m = mBase + wrow * 64 + i * 16 + q * 4;
        int b = m >> 11, t = m & 2047;
        uint32_t lo = pk2bf(acc[i][jj][0] + bb[jj], acc[i][jj][1] + bb[jj]);
        uint32_t hi = pk2bf(acc[i][jj][2] + bb[jj], acc[i][jj][3] + bb[jj]);
        *(uint2*)(Co + (size_t)((b * 16 + h) * 64 + d) * 2048 + t) = make_uint2(lo, hi);
      }
  }
}

// Q/K/V projections, A read directly from fp32 inputs (fused conversion).
// XCD swizzle, bx inner: per XCD one 512KB fp32 A-panel's 8 x-tiles run
// together (A stays hot in L2; 2MB Bt panel set resident alongside).
__global__ __launch_bounds__(256, 2)
void gemm_qkv(const float* __restrict__ qs, const float* __restrict__ ks,
              const float* __restrict__ vs, const uint16_t* __restrict__ Wtq,
              const uint16_t* __restrict__ Wtk, const uint16_t* __restrict__ Wtv,
              const float* __restrict__ bq, const float* __restrict__ bk,
              const float* __restrict__ bv, uint16_t* __restrict__ Qp,
              uint16_t* __restrict__ Kp, uint16_t* __restrict__ Vt, float cs) {
  __shared__ uint16_t lA[8192], lB[8192];
  int id = blockIdx.x + (blockIdx.y << 3) + (blockIdx.z << 9);  // 0..1535
  int xcd = id & 7, j = id >> 3;                                // j: 0..191
  int bx = j & 7;
  int by = xcd * 8 + ((j >> 3) & 7);
  int z  = j >> 6;
  const void* A      = z == 0 ? (const void*)qs : (z == 1 ? (const void*)ks : (const void*)vs);
  const uint16_t* Bt = z == 0 ? Wtq : (z == 1 ? Wtk : Wtv);
  const float* bias  = z == 0 ? bq : (z == 1 ? bk : bv);
  void* C            = z == 0 ? (void*)Qp : (z == 1 ? (void*)Kp : (void*)Vt);
  int mode   = z == 2 ? 2 : 1;
  float os   = z == 0 ? cs : 1.0f;
  gemm_body<true>(A, Bt, bias, C, 1024, 1024, mode, os, by * 128, bx * 128, lA, lB);
}

__global__ __launch_bounds__(256, 2)
void gemm_out(const uint16_t* __restrict__ A, const uint16_t* __restrict__ Bt,
              const float* __restrict__ bias, float* __restrict__ C) {
  __shared__ uint16_t lA[8192], lB[8192];
  int id = blockIdx.x + (blockIdx.y << 3);  // 0..511
  int xcd = id & 7, j = id >> 3;            // j: 0..63
  int bx = j & 7;
  int by = xcd * 8 + (j >> 3);
  gemm_body<false>(A, Bt, bias, C, 1024, 1024, 0, 1.0f, by * 128, bx * 128, lA, lB);
}

// ---------------- flash attention (R10, proven 87.3us) ----------------------
// grid (16, 64), 256 threads (4 waves).  XCD swizzle: XCD k owns bh in
// [8k,8k+8) (its K+V = 4MB = its L2).  S^T = K*Q^T; Q pre-scaled by
// 0.125*log2e -> p = exp2(s), no online max.
// 64-key K/V tiles double-buffered in 32KiB:
//   lds[    0.. 4096) = K buf0    lds[ 4096.. 8192) = K buf1
//   lds[ 8192..12288) = V buf0    lds[12288..16384) = V buf1
// Key-pair structure: per 32-key pair, QK MFMA-A takes A-row m from key
// (m>>2)*8+(m&3), second MFMA +4.  Lane (q,c) then holds P for keys q*8..q*8+7
// == the B-fragment of mfma_f32_16x16x32_bf16, so PV and lacc run at K=32.
__global__ __launch_bounds__(256, 2)
void attn(const uint16_t* __restrict__ Qp, const uint16_t* __restrict__ Kp,
          const uint16_t* __restrict__ Vt, uint16_t* __restrict__ Ob) {
  __shared__ uint16_t lds[16384];
  int tid = threadIdx.x, wave = tid >> 6, lane = tid & 63;
  int q = lane >> 4, c = lane & 15;
  int cs = c & 7;
  int gq   = (c & 3) | (((c >> 2) & 1) << 2);  // K-read swizzle term
  int rowA = ((c >> 2) << 3) + (c & 3);        // K row within 32-key pair (MFMA-A)

  int id = blockIdx.y * 16 + blockIdx.x;     // 0..1023
  int wk = (id & 7) * 128 + (id >> 3);       // bijective XCD grouping
  int qt = wk & 15, bh = wk >> 4;
  int b = bh >> 4, h = bh & 15;
  int qbase = qt * 128;
  int swz = ((lane & 7) ^ (lane >> 3)) * 8;  // r&7 swizzle (Q and V staging)

  {  // stage Q tile (128 x 64) into lds[0..8192), r&7-swizzled
    const uint16_t* gQ =
        Qp + (size_t)(b * 2048 + qbase + wave * 32 + (lane >> 3)) * 1024 + h * 64 + swz;
#pragma unroll
    for (int it = 0; it < 4; it++)
      gl2lds16(gQ + (size_t)(it * 8) * 1024, &lds[(wave * 32 + it * 8) * 64]);
  }
  __syncthreads();
  bf16x8 qf[2][2];
#pragma unroll
  for (int it = 0; it < 2; it++)
#pragma unroll
    for (int kk = 0; kk < 2; kk++)
      qf[it][kk] =
          *(const bf16x8*)&lds[(wave * 32 + it * 16 + c) * 64 + ((kk * 4 + q) ^ cs) * 8];
  __syncthreads();  // all waves' qf reads done before K tile 0 overwrites Q

  f32x4 o[4][2] = {};
  f32x4 lacc[2] = {};
  union { uint32_t u[4]; bf16x8 v; } one8;
  one8.u[0] = one8.u[1] = one8.u[2] = one8.u[3] = 0x3F803F80u;  // bf16 1.0 x8

  // K staging with g-swizzle: wave stages rows wave*16+it*8+rho; content chunk
  // at position p is p ^ ((rho&3) | (it<<2)).
  int kchunk = (lane & 7) ^ ((lane >> 3) & 3);
  const uint16_t* gKa =
      Kp + (size_t)(b * 2048 + wave * 16 + (lane >> 3)) * 1024 + h * 64 + kchunk * 8;
  const uint16_t* gKb =
      Kp + (size_t)(b * 2048 + wave * 16 + 8 + (lane >> 3)) * 1024 + h * 64 + (kchunk ^ 4) * 8;
  const uint16_t* gV0 = Vt + (size_t)(bh * 64 + wave * 16 + (lane >> 3)) * 2048 + swz;

  auto stage = [&](int tile, int nb) {
    gl2lds16(gKa + (size_t)(tile * 64) * 1024, &lds[nb + (wave * 16) * 64]);
    gl2lds16(gKb + (size_t)(tile * 64) * 1024, &lds[nb + (wave * 16 + 8) * 64]);
    gl2lds16(gV0 + (size_t)(tile * 64), &lds[8192 + nb + (wave * 16) * 64]);
    gl2lds16(gV0 + (size_t)(8 * 2048) + tile * 64, &lds[8192 + nb + (wave * 16 + 8) * 64]);
  };

  auto compute = [&](const uint16_t* sKc, const uint16_t* sVc) {
    f32x4 s[2][2][2];  // [pair][keyhalf A/B][query-half it]
#pragma unroll
    for (int p = 0; p < 2; p++) {
      const uint16_t* kr = &sKc[(p * 32 + rowA) * 64];
      bf16x8 aA0 = *(const bf16x8*)&kr[(q ^ gq) * 8];
      bf16x8 aA1 = *(const bf16x8*)&kr[((4 + q) ^ gq) * 8];
      bf16x8 aB0 = *(const bf16x8*)&kr[256 + (q ^ gq) * 8];
      bf16x8 aB1 = *(const bf16x8*)&kr[256 + ((4 + q) ^ gq) * 8];
      s[p][0][0] = __builtin_amdgcn_mfma_f32_16x16x32_bf16(aA0, qf[0][0],
                                                           (f32x4){0.f, 0.f, 0.f, 0.f}, 0, 0, 0);
      s[p][0][0] = __builtin_amdgcn_mfma_f32_16x16x32_bf16(aA1, qf[0][1], s[p][0][0], 0, 0, 0);
      s[p][0][1] = __builtin_amdgcn_mfma_f32_16x16x32_bf16(aA0, qf[1][0],
                                                           (f32x4){0.f, 0.f, 0.f, 0.f}, 0, 0, 0);
      s[p][0][1] = __builtin_amdgcn_mfma_f32_16x16x32_bf16(aA1, qf[1][1], s[p][0][1], 0, 0, 0);
      s[p][1][0] = __builtin_amdgcn_mfma_f32_16x16x32_bf16(aB0, qf[0][0],
                                                           (f32x4){0.f, 0.f, 0.f, 0.f}, 0, 0, 0);
      s[p][1][0] = __builtin_amdgcn_mfma_f32_16x16x32_bf16(aB1, qf[0][1], s[p][1][0], 0, 0, 0);
      s[p][1][1] = __builtin_amdgcn_mfma_f32_16x16x32_bf16(aB0, qf[1][0],
                                                           (f32x4){0.f, 0.f, 0.f, 0.f}, 0, 0, 0);
      s[p][1][1] = __builtin_amdgcn_mfma_f32_16x16x32_bf16(aB1, qf[1][1], s[p][1][1], 0, 0, 0);
    }
#pragma unroll
    for (int p = 0; p < 2; p++) {
      union { uint32_t u[4]; bf16x8 v; } pb[2];
#pragma unroll
      for (int it = 0; it < 2; it++) {
        float a0 = __builtin_amdgcn_exp2f(s[p][0][it][0]);
        float a1 = __builtin_amdgcn_exp2f(s[p][0][it][1]);
        float a2 = __builtin_amdgcn_exp2f(s[p][0][it][2]);
        float a3 = __builtin_amdgcn_exp2f(s[p][0][it][3]);
        float b0 = __builtin_amdgcn_exp2f(s[p][1][it][0]);
        float b1 = __builtin_amdgcn_exp2f(s[p][1][it][1]);
        float b2 = __builtin_amdgcn_exp2f(s[p][1][it][2]);
        float b3 = __builtin_amdgcn_exp2f(s[p][1][it][3]);
        pb[it].u[0] = pk2bf(a0, a1); pb[it].u[1] = pk2bf(a2, a3);
        pb[it].u[2] = pk2bf(b0, b1); pb[it].u[3] = pk2bf(b2, b3);
      }
      // softmax denominator on the MFMA pipe at K=32
      lacc[0] = __builtin_amdgcn_mfma_f32_16x16x32_bf16(one8.v, pb[0].v, lacc[0], 0, 0, 0);
      lacc[1] = __builtin_amdgcn_mfma_f32_16x16x32_bf16(one8.v, pb[1].v, lacc[1], 0, 0, 0);
#pragma unroll
      for (int mt = 0; mt < 4; mt++) {
        bf16x8 vv = *(const bf16x8*)&sVc[(mt * 16 + c) * 64 + (((p * 4 + q) ^ cs) * 8)];
        o[mt][0] = __builtin_amdgcn_mfma_f32_16x16x32_bf16(vv, pb[0].v, o[mt][0], 0, 0, 0);
        o[mt][1] = __builtin_amdgcn_mfma_f32_16x16x32_bf16(vv, pb[1].v, o[mt][1], 0, 0, 0);
      }
    }
  };

  stage(0, 0);  // prologue: tile 0 -> buf 0
  for (int kt2 = 0; kt2 < 16; kt2++) {
    __syncthreads();                       // tile 2*kt2 resident in buf0
    stage(kt2 * 2 + 1, 4096);              // prefetch odd tile -> buf1
    compute(&lds[0], &lds[8192]);
    __syncthreads();                       // tile 2*kt2+1 resident in buf1
    if (kt2 < 15) stage(kt2 * 2 + 2, 0);   // prefetch even tile -> buf0
    compute(&lds[4096], &lds[12288]);
  }

  // l = column sums (all rows/regs of lacc identical) -- no shuffles needed
  float l[2] = {lacc[0][0], lacc[1][0]};

  // epilogue: attn[t][h*64+d] bf16, 4 consecutive d per 8B store
#pragma unroll
  for (int it = 0; it < 2; it++) {
    float inv = 1.0f / l[it];
    size_t trow = (size_t)(b * 2048 + qbase + wave * 32 + it * 16 + c) * 1024 + h * 64;
#pragma unroll
    for (int mt = 0; mt < 4; mt++) {
      uint32_t lo = pk2bf(o[mt][it][0] * inv, o[mt][it][1] * inv);
      uint32_t hi = pk2bf(o[mt][it][2] * inv, o[mt][it][3] * inv);
      *(uint2*)(Ob + trow + mt * 16 + q * 4) = make_uint2(lo, hi);
    }
  }
}

extern "C" void kernel_launch(void* const* d_in, const int* in_sizes, int n_in,
                              void* d_out, int out_size, void* d_ws, size_t ws_size,
                              hipStream_t stream) {
  (void)in_sizes; (void)n_in; (void)out_size; (void)ws_size;
  const float* query = (const float*)d_in[0];
  const float* key_  = (const float*)d_in[1];
  const float* value = (const float*)d_in[2];
  const float* Wq = (const float*)d_in[3]; const float* bq = (const float*)d_in[4];
  const float* Wk = (const float*)d_in[5]; const float* bk = (const float*)d_in[6];
  const float* Wv = (const float*)d_in[7]; const float* bv = (const float*)d_in[8];
  const float* Wo = (const float*)d_in[9]; const float* bo = (const float*)d_in[10];

  const size_t SZ = (size_t)8192 * 1024;  // elements per (B*T, D) bf16 tensor
  uint16_t* buf0 = (uint16_t*)d_ws;       // (unused; was qb)
  uint16_t* buf1 = buf0 + SZ;             // (unused; was kb)
  uint16_t* buf2 = buf1 + SZ;             // attn-out
  uint16_t* buf3 = buf2 + SZ;             // Qp
  uint16_t* wts  = buf3 + SZ;             // 4 x 1M bf16 transposed weights
  uint16_t* Wtq = wts;
  uint16_t* Wtk = wts + 1048576;
  uint16_t* Wtv = wts + 2097152;
  uint16_t* Wto = wts + 3145728;
  uint16_t* Kp  = wts + 4194304;
  uint16_t* Vt  = Kp + SZ;

  const float Cs = 0.125f * LOG2E;  // folded into Q projection

  transpose_weights<<<dim3(32, 32, 4), 256, 0, stream>>>(Wq, Wk, Wv, Wo, wts);
  gemm_qkv<<<dim3(8, 64, 3), 256, 0, stream>>>(query, key_, value, Wtq, Wtk, Wtv,
                                               bq, bk, bv, buf3, Kp, Vt, Cs);
  attn<<<dim3(16, 64), 256, 0, stream>>>(buf3, Kp, Vt, buf2);
  gemm_out<<<dim3(8, 64), 256, 0, stream>>>(buf2, Wto, bo, (float*)d_out);
}

// Round 8
// 350.226 us; speedup vs baseline: 1.0641x; 1.0641x over previous
//
#include <hip/hip_runtime.h>
#include <hip/hip_bf16.h>
#include <stdint.h>

// MHA forward: B=4, T=2048, D=1024, H=16, dk=64.  fp32 in/out, bf16 MFMA internally.
// R3: XOR bank-swizzle on all LDS tiles. R4: softmax de-VALU-ized.
// R7: attn: 64-key K/V dbuf tiles, prefetch-after-barrier; XCD swizzle.
// R10: attn PV at K=32 via key-pair remap -> 87.3us, 0 bank conflicts.  KEPT.
// R11 lesson: deeper per-wave blocking in attn regressed (wave-overlap-bound).
// R12 lesson: fused fp32->bf16 A-staging correct but issue-then-drain left
//      gemm_qkv latency-bound (149us, MfmaUtil 13.8%, HBM 10.5%).
// R13 lesson: dbuf schedule was right but nb=4096 was attn's 64x64 tile size;
//      GEMM tiles are 128x64 = 8192 elems -> buf1 overlapped buf0 rows 64-127
//      -> prefetch corrupted live tile (absmax 0.078).  FIX: nb=8192.
// R13b: gemm_body double-buffered (64KB LDS, 2 blocks/CU), prefetch-after-
//      barrier; T14 for fp32 A (issue loads early, hold in regs across
//      compute, cvt+ds_write late).  convert_inputs stays eliminated.

typedef __bf16 bf16x8 __attribute__((ext_vector_type(8)));
typedef float  f32x4  __attribute__((ext_vector_type(4)));

#define LOG2E 1.44269504088896340736f

static __device__ __forceinline__ uint32_t f2bf(float x) {
  uint32_t u = __float_as_uint(x);
  u += 0x7fffu + ((u >> 16) & 1u);      // RNE
  return u >> 16;
}
#if __has_builtin(__builtin_amdgcn_cvt_pk_bf16_f32)
static __device__ __forceinline__ uint32_t pk2bf(float a, float b) {
  typedef __bf16 b2 __attribute__((ext_vector_type(2)));
  union { b2 v; uint32_t u; } x;
  x.v = __builtin_amdgcn_cvt_pk_bf16_f32(a, b);  // lo=a, hi=b
  return x.u;
}
#else
static __device__ __forceinline__ uint32_t pk2bf(float a, float b) {
  return f2bf(a) | (f2bf(b) << 16);
}
#endif
static __device__ __forceinline__ void gl2lds16(const void* g, void* l) {
  // async global->LDS, 16B/lane; LDS dest = wave-uniform base + lane*16
  __builtin_amdgcn_global_load_lds(
      (const __attribute__((address_space(1))) uint32_t*)g,
      (__attribute__((address_space(3))) uint32_t*)l, 16, 0, 0);
}

// ---------------- W (K x N fp32) -> Wt (N x K bf16) ------------------------
__global__ void transpose_weights(const float* __restrict__ Wq, const float* __restrict__ Wk,
                                  const float* __restrict__ Wv, const float* __restrict__ Wo,
                                  uint16_t* __restrict__ out) {
  __shared__ float t[32][33];
  const float* W = blockIdx.z == 0 ? Wq : blockIdx.z == 1 ? Wk : blockIdx.z == 2 ? Wv : Wo;
  uint16_t* O = out + (size_t)blockIdx.z * 1048576;
  int tx = threadIdx.x & 31, ty = threadIdx.x >> 5;
  int r0 = blockIdx.y * 32, c0 = blockIdx.x * 32;
#pragma unroll
  for (int i = 0; i < 4; i++) t[ty + i * 8][tx] = W[(size_t)(r0 + ty + i * 8) * 1024 + c0 + tx];
  __syncthreads();
#pragma unroll
  for (int i = 0; i < 4; i++)
    O[(size_t)(c0 + ty + i * 8) * 1024 + r0 + tx] = (uint16_t)f2bf(t[tx][ty + i * 8]);
}

// ---------------- bf16 GEMM body: C = (A(MxK) * Bt(NxK)^T + bias) * oscale -
// Double-buffered 128x64 LDS tiles (8192 elems each; bufs at 0 / 8192);
// XOR chunk swizzle by row&7.
// AF32: A fp32, reg-staged (issue-early/write-late) + cvt_pk + ds_write.
//       else A bf16 via async gl2lds.  B always async gl2lds.
// mode 0: fp32 natural   mode 1: bf16 natural   mode 2: bf16 V-transposed per head
template <bool AF32>
static __device__ __forceinline__ void gemm_body(
    const void* __restrict__ Ain, const uint16_t* __restrict__ Bt,
    const float* __restrict__ bias, void* __restrict__ Cout,
    int N, int K, int mode, float oscale, int mBase, int nBase,
    uint16_t* __restrict__ lA, uint16_t* __restrict__ lB) {
  int tid = threadIdx.x, wave = tid >> 6, lane = tid & 63;
  int q = lane >> 4, c = lane & 15;
  int wrow = wave & 1, wcol = wave >> 1;
  f32x4 acc[4][4] = {};

  int rho = lane >> 3, j = lane & 7;
  int swz = (j ^ rho) * 8;
  const uint16_t* gB   = Bt + (size_t)(nBase + wave * 32 + rho) * K + swz;
  const uint16_t* gA16 = (const uint16_t*)Ain + (size_t)(mBase + wave * 32 + rho) * K + swz;
  const float*    gA32 = (const float*)Ain + (size_t)(mBase + wave * 32 + rho) * K + swz;
  int cs = c & 7;

  float4 fa[4][2];  // held A tile (AF32), in flight across compute

  auto issueA32 = [&](int kt) {
#pragma unroll
    for (int it = 0; it < 4; it++) {
      const float* p = gA32 + (size_t)(it * 8) * K + kt * 64;
      fa[it][0] = *(const float4*)p;
      fa[it][1] = *(const float4*)(p + 4);
    }
  };
  auto writeA32 = [&](int nb) {
#pragma unroll
    for (int it = 0; it < 4; it++) {
      uint4 ov;
      ov.x = pk2bf(fa[it][0].x, fa[it][0].y);
      ov.y = pk2bf(fa[it][0].z, fa[it][0].w);
      ov.z = pk2bf(fa[it][1].x, fa[it][1].y);
      ov.w = pk2bf(fa[it][1].z, fa[it][1].w);
      *(uint4*)&lA[nb + (wave * 32 + it * 8 + rho) * 64 + j * 8] = ov;
    }
  };
  auto issueA16 = [&](int kt, int nb) {
#pragma unroll
    for (int it = 0; it < 4; it++)
      gl2lds16(gA16 + (size_t)(it * 8) * K + kt * 64, &lA[nb + (wave * 32 + it * 8) * 64]);
  };
  auto issueB = [&](int kt, int nb) {
#pragma unroll
    for (int it = 0; it < 4; it++)
      gl2lds16(gB + (size_t)(it * 8) * K + kt * 64, &lB[nb + (wave * 32 + it * 8) * 64]);
  };
  auto compute = [&](int nb) {
#pragma unroll
    for (int kk = 0; kk < 2; kk++) {
      bf16x8 af[4], bfr[4];
#pragma unroll
      for (int i = 0; i < 4; i++)
        af[i] = *(const bf16x8*)&lA[nb + (wrow * 64 + i * 16 + c) * 64 + ((kk * 4 + q) ^ cs) * 8];
#pragma unroll
      for (int jj = 0; jj < 4; jj++)
        bfr[jj] = *(const bf16x8*)&lB[nb + (wcol * 64 + jj * 16 + c) * 64 + ((kk * 4 + q) ^ cs) * 8];
#pragma unroll
      for (int i = 0; i < 4; i++)
#pragma unroll
        for (int jj = 0; jj < 4; jj++)
          acc[i][jj] = __builtin_amdgcn_mfma_f32_16x16x32_bf16(af[i], bfr[jj], acc[i][jj], 0, 0, 0);
    }
  };

  // prologue: tile 0 -> buf0 ([0, 8192))
  if (AF32) { issueA32(0); writeA32(0); } else issueA16(0, 0);
  issueB(0, 0);

  // K/64 = 16 tiles, 2 per iteration, double-buffered prefetch-after-barrier.
  // Buffers: buf0 = 0, buf1 = 8192 (tile = 128x64 = 8192 elems).
  for (int kt2 = 0; kt2 < 8; kt2++) {
    __syncthreads();                       // buf0 tile 2*kt2 ready
    if (AF32) issueA32(kt2 * 2 + 1); else issueA16(kt2 * 2 + 1, 8192);
    issueB(kt2 * 2 + 1, 8192);
    compute(0);
    if (AF32) writeA32(8192);              // vmcnt wait covered by compute(0)
    __syncthreads();                       // buf1 tile 2*kt2+1 ready
    if (kt2 < 7) {
      if (AF32) issueA32(kt2 * 2 + 2); else issueA16(kt2 * 2 + 2, 0);
      issueB(kt2 * 2 + 2, 0);
    }
    compute(8192);
    if (AF32 && kt2 < 7) writeA32(0);
  }

  float bb[4];
#pragma unroll
  for (int jj = 0; jj < 4; jj++) bb[jj] = bias[nBase + wcol * 64 + jj * 16 + c];

  if (mode == 0) {
    float* Co = (float*)Cout;
#pragma unroll
    for (int i = 0; i < 4; i++)
#pragma unroll
      for (int jj = 0; jj < 4; jj++) {
        int row = mBase + wrow * 64 + i * 16 + q * 4;
        int col = nBase + wcol * 64 + jj * 16 + c;
#pragma unroll
        for (int r = 0; r < 4; r++) Co[(size_t)(row + r) * N + col] = acc[i][jj][r] + bb[jj];
      }
  } else if (mode == 1) {
    uint16_t* Co = (uint16_t*)Cout;
#pragma unroll
    for (int i = 0; i < 4; i++)
#pragma unroll
      for (int jj = 0; jj < 4; jj++) {
        int row = mBase + wrow * 64 + i * 16 + q * 4;
        int col = nBase + wcol * 64 + jj * 16 + c;
#pragma unroll
        for (int r = 0; r < 4; r++)
          Co[(size_t)(row + r) * N + col] = (uint16_t)f2bf((acc[i][jj][r] + bb[jj]) * oscale);
      }
  } else {  // V: write Vt[(b*16+h)*64+d][t]
    uint16_t* Co = (uint16_t*)Cout;
#pragma unroll
    for (int i = 0; i < 4; i++)
#pragma unroll
      for (int jj = 0; jj < 4; jj++) {
        int n = nBase + wcol * 64 + jj * 16 + c;
        int h = n >> 6, d = n & 63;
        int m = mBase + wrow * 64 + i * 16 + q * 4;
        int b = m >> 11, t = m & 2047;
        uint32_t lo = pk2bf(acc[i][jj][0] + bb[jj], acc[i][jj][1] + bb[jj]);
        uint32_t hi = pk2bf(acc[i][jj][2] + bb[jj], acc[i][jj][3] + bb[jj]);
        *(uint2*)(Co + (size_t)((b * 16 + h) * 64 + d) * 2048 + t) = make_uint2(lo, hi);
      }
  }
}

// Q/K/V projections, A read directly from fp32 inputs (fused conversion).
// XCD swizzle, bx inner: per XCD one 512KB fp32 A-panel's 8 x-tiles run
// together (A hot in L2; 2MB Bt set resident alongside).
__global__ __launch_bounds__(256, 2)
void gemm_qkv(const float* __restrict__ qs, const float* __restrict__ ks,
              const float* __restrict__ vs, const uint16_t* __restrict__ Wtq,
              const uint16_t* __restrict__ Wtk, const uint16_t* __restrict__ Wtv,
              const float* __restrict__ bq, const float* __restrict__ bk,
              const float* __restrict__ bv, uint16_t* __restrict__ Qp,
              uint16_t* __restrict__ Kp, uint16_t* __restrict__ Vt, float cs) {
  __shared__ uint16_t lA[16384], lB[16384];
  int id = blockIdx.x + (blockIdx.y << 3) + (blockIdx.z << 9);  // 0..1535
  int xcd = id & 7, j = id >> 3;                                // j: 0..191
  int bx = j & 7;
  int by = xcd * 8 + ((j >> 3) & 7);
  int z  = j >> 6;
  const void* A      = z == 0 ? (const void*)qs : (z == 1 ? (const void*)ks : (const void*)vs);
  const uint16_t* Bt = z == 0 ? Wtq : (z == 1 ? Wtk : Wtv);
  const float* bias  = z == 0 ? bq : (z == 1 ? bk : bv);
  void* C            = z == 0 ? (void*)Qp : (z == 1 ? (void*)Kp : (void*)Vt);
  int mode   = z == 2 ? 2 : 1;
  float os   = z == 0 ? cs : 1.0f;
  gemm_body<true>(A, Bt, bias, C, 1024, 1024, mode, os, by * 128, bx * 128, lA, lB);
}

__global__ __launch_bounds__(256, 2)
void gemm_out(const uint16_t* __restrict__ A, const uint16_t* __restrict__ Bt,
              const float* __restrict__ bias, float* __restrict__ C) {
  __shared__ uint16_t lA[16384], lB[16384];
  int id = blockIdx.x + (blockIdx.y << 3);  // 0..511
  int xcd = id & 7, j = id >> 3;            // j: 0..63
  int bx = j & 7;
  int by = xcd * 8 + (j >> 3);
  gemm_body<false>(A, Bt, bias, C, 1024, 1024, 0, 1.0f, by * 128, bx * 128, lA, lB);
}

// ---------------- flash attention (R10, proven 87.3us) ----------------------
// grid (16, 64), 256 threads (4 waves).  XCD swizzle: XCD k owns bh in
// [8k,8k+8) (its K+V = 4MB = its L2).  S^T = K*Q^T; Q pre-scaled by
// 0.125*log2e -> p = exp2(s), no online max.
// 64-key K/V tiles double-buffered in 32KiB:
//   lds[    0.. 4096) = K buf0    lds[ 4096.. 8192) = K buf1
//   lds[ 8192..12288) = V buf0    lds[12288..16384) = V buf1
// Key-pair structure: per 32-key pair, QK MFMA-A takes A-row m from key
// (m>>2)*8+(m&3), second MFMA +4.  Lane (q,c) then holds P for keys q*8..q*8+7
// == the B-fragment of mfma_f32_16x16x32_bf16, so PV and lacc run at K=32.
__global__ __launch_bounds__(256, 2)
void attn(const uint16_t* __restrict__ Qp, const uint16_t* __restrict__ Kp,
          const uint16_t* __restrict__ Vt, uint16_t* __restrict__ Ob) {
  __shared__ uint16_t lds[16384];
  int tid = threadIdx.x, wave = tid >> 6, lane = tid & 63;
  int q = lane >> 4, c = lane & 15;
  int cs = c & 7;
  int gq   = (c & 3) | (((c >> 2) & 1) << 2);  // K-read swizzle term
  int rowA = ((c >> 2) << 3) + (c & 3);        // K row within 32-key pair (MFMA-A)

  int id = blockIdx.y * 16 + blockIdx.x;     // 0..1023
  int wk = (id & 7) * 128 + (id >> 3);       // bijective XCD grouping
  int qt = wk & 15, bh = wk >> 4;
  int b = bh >> 4, h = bh & 15;
  int qbase = qt * 128;
  int swz = ((lane & 7) ^ (lane >> 3)) * 8;  // r&7 swizzle (Q and V staging)

  {  // stage Q tile (128 x 64) into lds[0..8192), r&7-swizzled
    const uint16_t* gQ =
        Qp + (size_t)(b * 2048 + qbase + wave * 32 + (lane >> 3)) * 1024 + h * 64 + swz;
#pragma unroll
    for (int it = 0; it < 4; it++)
      gl2lds16(gQ + (size_t)(it * 8) * 1024, &lds[(wave * 32 + it * 8) * 64]);
  }
  __syncthreads();
  bf16x8 qf[2][2];
#pragma unroll
  for (int it = 0; it < 2; it++)
#pragma unroll
    for (int kk = 0; kk < 2; kk++)
      qf[it][kk] =
          *(const bf16x8*)&lds[(wave * 32 + it * 16 + c) * 64 + ((kk * 4 + q) ^ cs) * 8];
  __syncthreads();  // all waves' qf reads done before K tile 0 overwrites Q

  f32x4 o[4][2] = {};
  f32x4 lacc[2] = {};
  union { uint32_t u[4]; bf16x8 v; } one8;
  one8.u[0] = one8.u[1] = one8.u[2] = one8.u[3] = 0x3F803F80u;  // bf16 1.0 x8

  // K staging with g-swizzle: wave stages rows wave*16+it*8+rho; content chunk
  // at position p is p ^ ((rho&3) | (it<<2)).
  int kchunk = (lane & 7) ^ ((lane >> 3) & 3);
  const uint16_t* gKa =
      Kp + (size_t)(b * 2048 + wave * 16 + (lane >> 3)) * 1024 + h * 64 + kchunk * 8;
  const uint16_t* gKb =
      Kp + (size_t)(b * 2048 + wave * 16 + 8 + (lane >> 3)) * 1024 + h * 64 + (kchunk ^ 4) * 8;
  const uint16_t* gV0 = Vt + (size_t)(bh * 64 + wave * 16 + (lane >> 3)) * 2048 + swz;

  auto stage = [&](int tile, int nb) {
    gl2lds16(gKa + (size_t)(tile * 64) * 1024, &lds[nb + (wave * 16) * 64]);
    gl2lds16(gKb + (size_t)(tile * 64) * 1024, &lds[nb + (wave * 16 + 8) * 64]);
    gl2lds16(gV0 + (size_t)(tile * 64), &lds[8192 + nb + (wave * 16) * 64]);
    gl2lds16(gV0 + (size_t)(8 * 2048) + tile * 64, &lds[8192 + nb + (wave * 16 + 8) * 64]);
  };

  auto compute = [&](const uint16_t* sKc, const uint16_t* sVc) {
    f32x4 s[2][2][2];  // [pair][keyhalf A/B][query-half it]
#pragma unroll
    for (int p = 0; p < 2; p++) {
      const uint16_t* kr = &sKc[(p * 32 + rowA) * 64];
      bf16x8 aA0 = *(const bf16x8*)&kr[(q ^ gq) * 8];
      bf16x8 aA1 = *(const bf16x8*)&kr[((4 + q) ^ gq) * 8];
      bf16x8 aB0 = *(const bf16x8*)&kr[256 + (q ^ gq) * 8];
      bf16x8 aB1 = *(const bf16x8*)&kr[256 + ((4 + q) ^ gq) * 8];
      s[p][0][0] = __builtin_amdgcn_mfma_f32_16x16x32_bf16(aA0, qf[0][0],
                                                           (f32x4){0.f, 0.f, 0.f, 0.f}, 0, 0, 0);
      s[p][0][0] = __builtin_amdgcn_mfma_f32_16x16x32_bf16(aA1, qf[0][1], s[p][0][0], 0, 0, 0);
      s[p][0][1] = __builtin_amdgcn_mfma_f32_16x16x32_bf16(aA0, qf[1][0],
                                                           (f32x4){0.f, 0.f, 0.f, 0.f}, 0, 0, 0);
      s[p][0][1] = __builtin_amdgcn_mfma_f32_16x16x32_bf16(aA1, qf[1][1], s[p][0][1], 0, 0, 0);
      s[p][1][0] = __builtin_amdgcn_mfma_f32_16x16x32_bf16(aB0, qf[0][0],
                                                           (f32x4){0.f, 0.f, 0.f, 0.f}, 0, 0, 0);
      s[p][1][0] = __builtin_amdgcn_mfma_f32_16x16x32_bf16(aB1, qf[0][1], s[p][1][0], 0, 0, 0);
      s[p][1][1] = __builtin_amdgcn_mfma_f32_16x16x32_bf16(aB0, qf[1][0],
                                                           (f32x4){0.f, 0.f, 0.f, 0.f}, 0, 0, 0);
      s[p][1][1] = __builtin_amdgcn_mfma_f32_16x16x32_bf16(aB1, qf[1][1], s[p][1][1], 0, 0, 0);
    }
#pragma unroll
    for (int p = 0; p < 2; p++) {
      union { uint32_t u[4]; bf16x8 v; } pb[2];
#pragma unroll
      for (int it = 0; it < 2; it++) {
        float a0 = __builtin_amdgcn_exp2f(s[p][0][it][0]);
        float a1 = __builtin_amdgcn_exp2f(s[p][0][it][1]);
        float a2 = __builtin_amdgcn_exp2f(s[p][0][it][2]);
        float a3 = __builtin_amdgcn_exp2f(s[p][0][it][3]);
        float b0 = __builtin_amdgcn_exp2f(s[p][1][it][0]);
        float b1 = __builtin_amdgcn_exp2f(s[p][1][it][1]);
        float b2 = __builtin_amdgcn_exp2f(s[p][1][it][2]);
        float b3 = __builtin_amdgcn_exp2f(s[p][1][it][3]);
        pb[it].u[0] = pk2bf(a0, a1); pb[it].u[1] = pk2bf(a2, a3);
        pb[it].u[2] = pk2bf(b0, b1); pb[it].u[3] = pk2bf(b2, b3);
      }
      // softmax denominator on the MFMA pipe at K=32
      lacc[0] = __builtin_amdgcn_mfma_f32_16x16x32_bf16(one8.v, pb[0].v, lacc[0], 0, 0, 0);
      lacc[1] = __builtin_amdgcn_mfma_f32_16x16x32_bf16(one8.v, pb[1].v, lacc[1], 0, 0, 0);
#pragma unroll
      for (int mt = 0; mt < 4; mt++) {
        bf16x8 vv = *(const bf16x8*)&sVc[(mt * 16 + c) * 64 + (((p * 4 + q) ^ cs) * 8)];
        o[mt][0] = __builtin_amdgcn_mfma_f32_16x16x32_bf16(vv, pb[0].v, o[mt][0], 0, 0, 0);
        o[mt][1] = __builtin_amdgcn_mfma_f32_16x16x32_bf16(vv, pb[1].v, o[mt][1], 0, 0, 0);
      }
    }
  };

  stage(0, 0);  // prologue: tile 0 -> buf 0
  for (int kt2 = 0; kt2 < 16; kt2++) {
    __syncthreads();                       // tile 2*kt2 resident in buf0
    stage(kt2 * 2 + 1, 4096);              // prefetch odd tile -> buf1
    compute(&lds[0], &lds[8192]);
    __syncthreads();                       // tile 2*kt2+1 resident in buf1
    if (kt2 < 15) stage(kt2 * 2 + 2, 0);   // prefetch even tile -> buf0
    compute(&lds[4096], &lds[12288]);
  }

  // l = column sums (all rows/regs of lacc identical) -- no shuffles needed
  float l[2] = {lacc[0][0], lacc[1][0]};

  // epilogue: attn[t][h*64+d] bf16, 4 consecutive d per 8B store
#pragma unroll
  for (int it = 0; it < 2; it++) {
    float inv = 1.0f / l[it];
    size_t trow = (size_t)(b * 2048 + qbase + wave * 32 + it * 16 + c) * 1024 + h * 64;
#pragma unroll
    for (int mt = 0; mt < 4; mt++) {
      uint32_t lo = pk2bf(o[mt][it][0] * inv, o[mt][it][1] * inv);
      uint32_t hi = pk2bf(o[mt][it][2] * inv, o[mt][it][3] * inv);
      *(uint2*)(Ob + trow + mt * 16 + q * 4) = make_uint2(lo, hi);
    }
  }
}

extern "C" void kernel_launch(void* const* d_in, const int* in_sizes, int n_in,
                              void* d_out, int out_size, void* d_ws, size_t ws_size,
                              hipStream_t stream) {
  (void)in_sizes; (void)n_in; (void)out_size; (void)ws_size;
  const float* query = (const float*)d_in[0];
  const float* key_  = (const float*)d_in[1];
  const float* value = (const float*)d_in[2];
  const float* Wq = (const float*)d_in[3]; const float* bq = (const float*)d_in[4];
  const float* Wk = (const float*)d_in[5]; const float* bk = (const float*)d_in[6];
  const float* Wv = (const float*)d_in[7]; const float* bv = (const float*)d_in[8];
  const float* Wo = (const float*)d_in[9]; const float* bo = (const float*)d_in[10];

  const size_t SZ = (size_t)8192 * 1024;  // elements per (B*T, D) bf16 tensor
  uint16_t* buf0 = (uint16_t*)d_ws;       // (unused; was qb)
  uint16_t* buf1 = buf0 + SZ;             // (unused; was kb)
  uint16_t* buf2 = buf1 + SZ;             // attn-out
  uint16_t* buf3 = buf2 + SZ;             // Qp
  uint16_t* wts  = buf3 + SZ;             // 4 x 1M bf16 transposed weights
  uint16_t* Wtq = wts;
  uint16_t* Wtk = wts + 1048576;
  uint16_t* Wtv = wts + 2097152;
  uint16_t* Wto = wts + 3145728;
  uint16_t* Kp  = wts + 4194304;
  uint16_t* Vt  = Kp + SZ;

  const float Cs = 0.125f * LOG2E;  // folded into Q projection

  transpose_weights<<<dim3(32, 32, 4), 256, 0, stream>>>(Wq, Wk, Wv, Wo, wts);
  gemm_qkv<<<dim3(8, 64, 3), 256, 0, stream>>>(query, key_, value, Wtq, Wtk, Wtv,
                                               bq, bk, bv, buf3, Kp, Vt, Cs);
  attn<<<dim3(16, 64), 256, 0, stream>>>(buf3, Kp, Vt, buf2);
  gemm_out<<<dim3(8, 64), 256, 0, stream>>>(buf2, Wto, bo, (float*)d_out);
}